// Round 4
// baseline (182.567 us; speedup 1.0000x reference)
//
#include <hip/hip_runtime.h>
#include <cmath>

#define EMBED   1024
#define EPB     8
#define NB      64
#define KTOP    2
#define PARTS   16          // blocks per bucket in kernel C

// ---------------------------------------------------------------------------
// DPP helpers: full-wave64 sum without touching the DS pipe.
// After the 6 steps, lane 63 holds the sum of all 64 lanes.
// ---------------------------------------------------------------------------
template <int CTRL>
static __device__ __forceinline__ float dpp_mov(float v) {
    return __int_as_float(
        __builtin_amdgcn_update_dpp(0, __float_as_int(v), CTRL, 0xf, 0xf, true));
}
static __device__ __forceinline__ float wave_sum63(float x) {
    x += dpp_mov<0x111>(x);   // row_shr:1
    x += dpp_mov<0x112>(x);   // row_shr:2
    x += dpp_mov<0x114>(x);   // row_shr:4
    x += dpp_mov<0x118>(x);   // row_shr:8  -> lane15 of each row16 = row sum
    x += dpp_mov<0x142>(x);   // row_bcast15
    x += dpp_mov<0x143>(x);   // row_bcast31 -> lane63 = wave total
    return x;
}

// ---------------------------------------------------------------------------
// Kernel A: reciprocal L2 norms of 512 key rows + zero bucket counters.
// ---------------------------------------------------------------------------
__global__ void key_rnorm_kernel(const float* __restrict__ ek,
                                 float* __restrict__ rnorm,
                                 int* __restrict__ cnt, int nrows) {
    if (blockIdx.x == 0 && threadIdx.x < NB) cnt[threadIdx.x] = 0;
    int wave = (int)((blockIdx.x * blockDim.x + threadIdx.x) >> 6);
    int lane = threadIdx.x & 63;
    if (wave >= nrows) return;
    const float4* row = (const float4*)(ek + (size_t)wave * EMBED);
    float s = 0.f;
#pragma unroll
    for (int c = 0; c < 4; ++c) {
        float4 v = row[c * 64 + lane];
        s += v.x * v.x + v.y * v.y + v.z * v.z + v.w * v.w;
    }
#pragma unroll
    for (int off = 32; off; off >>= 1) s += __shfl_xor(s, off, 64);
    if (lane == 0) rnorm[wave] = 1.0f / fmaxf(sqrtf(s), 1e-12f);
}

// ---------------------------------------------------------------------------
// Kernel B: bucket compaction.
// ---------------------------------------------------------------------------
__global__ void compact_kernel(const int* __restrict__ op_id,
                               int* __restrict__ cnt,
                               int* __restrict__ list, int ntok) {
    int t = blockIdx.x * blockDim.x + threadIdx.x;
    if (t >= ntok) return;
    int b = op_id[t];
    b = min(max(b, 0), NB - 1);
    int slot = atomicAdd(&cnt[b], 1);
    list[(size_t)b * ntok + slot] = t;
}

// ---------------------------------------------------------------------------
// Epilogue for one token (runs exec-masked on lane 63).
// ---------------------------------------------------------------------------
static __device__ __forceinline__ void epilogue(
        int b, int t, float hh, const float* dot,
        float* __restrict__ out_gid, float* __restrict__ out_w) {
    float rh = 1.0f / fmaxf(sqrtf(hh), 1e-12f);
    float ex[EPB];
    float m = -1e30f;
#pragma unroll
    for (int e = 0; e < EPB; ++e) m = fmaxf(m, dot[e] * rh);
    float Z = 0.f;
#pragma unroll
    for (int e = 0; e < EPB; ++e) { ex[e] = expf(dot[e] * rh - m); Z += ex[e]; }
    int i1 = 0;
#pragma unroll
    for (int e = 1; e < EPB; ++e) if (ex[e] > ex[i1]) i1 = e;
    int i2 = (i1 == 0) ? 1 : 0;
#pragma unroll
    for (int e = 0; e < EPB; ++e)
        if (e != i1 && ex[e] > ex[i2]) i2 = e;
    float p1 = ex[i1] / Z;
    float p2 = ex[i2] / Z;
    float wsum = p1 + p2 + 1e-9f;
    float2 g = make_float2((float)(b * EPB + i1), (float)(b * EPB + i2));
    float2 w = make_float2(p1 / wsum, p2 / wsum);
    *(float2*)(out_gid + (size_t)t * KTOP) = g;
    *(float2*)(out_w   + (size_t)t * KTOP) = w;
}

// ---------------------------------------------------------------------------
// Kernel C: bucket-pinned router, keys in LDS, 2 tokens per wave-iter.
//  - 16 blocks per bucket x 64 buckets = 1024 blocks, 256 thr (4 waves).
//  - Block stages its bucket's 8 keys, pre-scaled by 1/||k||, into LDS (32KB).
//  - Each wave processes tokens (base+q, base+q+64), sharing every key
//    ds_read_b128 between both tokens.
//  - 9 partial sums per token reduced with DPP (VALU pipe, no DS).
// ---------------------------------------------------------------------------
__global__ __launch_bounds__(256, 4) void router_kernel(
        const float* __restrict__ h,
        const float* __restrict__ ek,
        const float* __restrict__ rk,
        const int*   __restrict__ cnt,
        const int*   __restrict__ list,
        float* __restrict__ out_gid,
        float* __restrict__ out_w,
        int ntok) {
    __shared__ float4 kl[EPB * 256];            // 32 KB: [e][c*64+lane]

    const int b    = blockIdx.x >> 4;           // bucket
    const int part = blockIdx.x & (PARTS - 1);
    const int tid  = threadIdx.x;
    const int wv   = tid >> 6;
    const int lane = tid & 63;

    // --- stage pre-scaled keys: 2048 float4 / 256 threads = 8 each ---
    const float4* k4 = (const float4*)ek + (size_t)b * (EPB * 256);
#pragma unroll
    for (int r = 0; r < 8; ++r) {
        int idx = r * 256 + tid;
        float s = rk[b * EPB + (idx >> 8)];
        float4 v = k4[idx];
        v.x *= s; v.y *= s; v.z *= s; v.w *= s;
        kl[idx] = v;
    }
    __syncthreads();

    const int  n  = cnt[b];
    const int  q  = part * 4 + wv;              // wave id within bucket [0,64)
    const int* ml = list + (size_t)b * ntok;

    for (int base = 0; base + q < n; base += 2 * 64) {
        int i0 = base + q;
        int i1 = i0 + 64;
        bool has1 = (i1 < n);
        int t0 = ml[i0];
        int t1 = has1 ? ml[i1] : t0;

        const float4* h0 = (const float4*)h + (size_t)t0 * 256;
        const float4* h1 = (const float4*)h + (size_t)t1 * 256;

        float4 a0[4], a1[4];
#pragma unroll
        for (int c = 0; c < 4; ++c) { a0[c] = h0[c * 64 + lane]; }
#pragma unroll
        for (int c = 0; c < 4; ++c) { a1[c] = h1[c * 64 + lane]; }

        float hh0 = 0.f, hh1 = 0.f;
#pragma unroll
        for (int c = 0; c < 4; ++c) {
            hh0 += a0[c].x * a0[c].x + a0[c].y * a0[c].y +
                   a0[c].z * a0[c].z + a0[c].w * a0[c].w;
            hh1 += a1[c].x * a1[c].x + a1[c].y * a1[c].y +
                   a1[c].z * a1[c].z + a1[c].w * a1[c].w;
        }

        float d0[EPB], d1[EPB];
#pragma unroll
        for (int e = 0; e < EPB; ++e) {
            float s0 = 0.f, s1 = 0.f;
#pragma unroll
            for (int c = 0; c < 4; ++c) {
                float4 kv = kl[e * 256 + c * 64 + lane];
                s0 += a0[c].x * kv.x + a0[c].y * kv.y +
                      a0[c].z * kv.z + a0[c].w * kv.w;
                s1 += a1[c].x * kv.x + a1[c].y * kv.y +
                      a1[c].z * kv.z + a1[c].w * kv.w;
            }
            d0[e] = s0; d1[e] = s1;
        }

        // DPP reductions (VALU pipe) -> totals in lane 63
        hh0 = wave_sum63(hh0);
        hh1 = wave_sum63(hh1);
#pragma unroll
        for (int e = 0; e < EPB; ++e) { d0[e] = wave_sum63(d0[e]); }
#pragma unroll
        for (int e = 0; e < EPB; ++e) { d1[e] = wave_sum63(d1[e]); }

        if (lane == 63) {
            epilogue(b, t0, hh0, d0, out_gid, out_w);
            if (has1) epilogue(b, t1, hh1, d1, out_gid, out_w);
        }
    }
}

extern "C" void kernel_launch(void* const* d_in, const int* in_sizes, int n_in,
                              void* d_out, int out_size, void* d_ws, size_t ws_size,
                              hipStream_t stream) {
    const float* h     = (const float*)d_in[0];
    const int*   op_id = (const int*)  d_in[1];
    const float* ek    = (const float*)d_in[2];

    int ntok  = in_sizes[1];           // B*T tokens
    int nrows = NB * EPB;              // 512 key rows

    // ws layout: rk (512 f) | cnt (64 i) | list (NB*ntok i)
    float* rk   = (float*)d_ws;
    int*   cnt  = (int*)(rk + 512);
    int*   list = cnt + 64;

    float* out_gid = (float*)d_out;
    float* out_w   = out_gid + (size_t)ntok * KTOP;

    int blocks1 = (nrows * 64 + 255) / 256;
    key_rnorm_kernel<<<blocks1, 256, 0, stream>>>(ek, rk, cnt, nrows);

    compact_kernel<<<(ntok + 255) / 256, 256, 0, stream>>>(op_id, cnt, list, ntok);

    router_kernel<<<NB * PARTS, 256, 0, stream>>>(h, ek, rk, cnt, list,
                                                  out_gid, out_w, ntok);
}

// Round 5
// 146.423 us; speedup vs baseline: 1.2468x; 1.2468x over previous
//
#include <hip/hip_runtime.h>
#include <cmath>

#define EMBED   1024
#define EPB     8
#define NB      64
#define KTOP    2
#define PARTS   16          // blocks per bucket in kernel C

// ---------------------------------------------------------------------------
// DPP helpers: full-wave64 sum without touching the DS pipe.
// After the 6 steps, lane 63 holds the sum of all 64 lanes.
// ---------------------------------------------------------------------------
template <int CTRL>
static __device__ __forceinline__ float dpp_mov(float v) {
    return __int_as_float(
        __builtin_amdgcn_update_dpp(0, __float_as_int(v), CTRL, 0xf, 0xf, true));
}
static __device__ __forceinline__ float wave_sum63(float x) {
    x += dpp_mov<0x111>(x);   // row_shr:1
    x += dpp_mov<0x112>(x);   // row_shr:2
    x += dpp_mov<0x114>(x);   // row_shr:4
    x += dpp_mov<0x118>(x);   // row_shr:8  -> lane15 of each row16 = row sum
    x += dpp_mov<0x142>(x);   // row_bcast15
    x += dpp_mov<0x143>(x);   // row_bcast31 -> lane63 = wave total
    return x;
}

// ---------------------------------------------------------------------------
// Kernel A: reciprocal L2 norms of 512 key rows + zero bucket counters.
// ---------------------------------------------------------------------------
__global__ void key_rnorm_kernel(const float* __restrict__ ek,
                                 float* __restrict__ rnorm,
                                 int* __restrict__ cnt, int nrows) {
    if (blockIdx.x == 0 && threadIdx.x < NB) cnt[threadIdx.x] = 0;
    int wave = (int)((blockIdx.x * blockDim.x + threadIdx.x) >> 6);
    int lane = threadIdx.x & 63;
    if (wave >= nrows) return;
    const float4* row = (const float4*)(ek + (size_t)wave * EMBED);
    float s = 0.f;
#pragma unroll
    for (int c = 0; c < 4; ++c) {
        float4 v = row[c * 64 + lane];
        s += v.x * v.x + v.y * v.y + v.z * v.z + v.w * v.w;
    }
#pragma unroll
    for (int off = 32; off; off >>= 1) s += __shfl_xor(s, off, 64);
    if (lane == 0) rnorm[wave] = 1.0f / fmaxf(sqrtf(s), 1e-12f);
}

// ---------------------------------------------------------------------------
// Kernel B: bucket compaction.
// ---------------------------------------------------------------------------
__global__ void compact_kernel(const int* __restrict__ op_id,
                               int* __restrict__ cnt,
                               int* __restrict__ list, int ntok) {
    int t = blockIdx.x * blockDim.x + threadIdx.x;
    if (t >= ntok) return;
    int b = op_id[t];
    b = min(max(b, 0), NB - 1);
    int slot = atomicAdd(&cnt[b], 1);
    list[(size_t)b * ntok + slot] = t;
}

// ---------------------------------------------------------------------------
// Epilogue for one token (runs exec-masked on lane 63).
// ---------------------------------------------------------------------------
static __device__ __forceinline__ void epilogue(
        int b, int t, float hh, const float* dot,
        float* __restrict__ out_gid, float* __restrict__ out_w) {
    float rh = 1.0f / fmaxf(sqrtf(hh), 1e-12f);
    float ex[EPB];
    float m = -1e30f;
#pragma unroll
    for (int e = 0; e < EPB; ++e) m = fmaxf(m, dot[e] * rh);
    float Z = 0.f;
#pragma unroll
    for (int e = 0; e < EPB; ++e) { ex[e] = expf(dot[e] * rh - m); Z += ex[e]; }
    int i1 = 0;
#pragma unroll
    for (int e = 1; e < EPB; ++e) if (ex[e] > ex[i1]) i1 = e;
    int i2 = (i1 == 0) ? 1 : 0;
#pragma unroll
    for (int e = 0; e < EPB; ++e)
        if (e != i1 && ex[e] > ex[i2]) i2 = e;
    float p1 = ex[i1] / Z;
    float p2 = ex[i2] / Z;
    float wsum = p1 + p2 + 1e-9f;
    float2 g = make_float2((float)(b * EPB + i1), (float)(b * EPB + i2));
    float2 w = make_float2(p1 / wsum, p2 / wsum);
    *(float2*)(out_gid + (size_t)t * KTOP) = g;
    *(float2*)(out_w   + (size_t)t * KTOP) = w;
}

// ---------------------------------------------------------------------------
// Kernel C: bucket-pinned router, keys in LDS, 2 tokens per wave-iter.
// R5 change vs R4: __launch_bounds__(256,2) instead of (256,4). R4's cap of
// 64 VGPRs spilled the whole 2-token working set to scratch (WRITE_SIZE
// 0.8 -> 77 MB was the tell). (256,2) allows up to 256 VGPRs; the working
// set (~110) fits with zero spills, LDS (32 KB) still allows 4-5 blocks/CU.
// ---------------------------------------------------------------------------
__global__ __launch_bounds__(256, 2) void router_kernel(
        const float* __restrict__ h,
        const float* __restrict__ ek,
        const float* __restrict__ rk,
        const int*   __restrict__ cnt,
        const int*   __restrict__ list,
        float* __restrict__ out_gid,
        float* __restrict__ out_w,
        int ntok) {
    __shared__ float4 kl[EPB * 256];            // 32 KB: [e][c*64+lane]

    const int b    = blockIdx.x >> 4;           // bucket
    const int part = blockIdx.x & (PARTS - 1);
    const int tid  = threadIdx.x;
    const int wv   = tid >> 6;
    const int lane = tid & 63;

    // --- stage pre-scaled keys: 2048 float4 / 256 threads = 8 each ---
    const float4* k4 = (const float4*)ek + (size_t)b * (EPB * 256);
#pragma unroll
    for (int r = 0; r < 8; ++r) {
        int idx = r * 256 + tid;
        float s = rk[b * EPB + (idx >> 8)];
        float4 v = k4[idx];
        v.x *= s; v.y *= s; v.z *= s; v.w *= s;
        kl[idx] = v;
    }
    __syncthreads();

    const int  n  = cnt[b];
    const int  q  = part * 4 + wv;              // wave id within bucket [0,64)
    const int* ml = list + (size_t)b * ntok;

    for (int base = 0; base + q < n; base += 2 * 64) {
        int i0 = base + q;
        int i1 = i0 + 64;
        bool has1 = (i1 < n);
        int t0 = ml[i0];
        int t1 = has1 ? ml[i1] : t0;

        const float4* h0 = (const float4*)h + (size_t)t0 * 256;
        const float4* h1 = (const float4*)h + (size_t)t1 * 256;

        float4 a0[4], a1[4];
#pragma unroll
        for (int c = 0; c < 4; ++c) { a0[c] = h0[c * 64 + lane]; }
#pragma unroll
        for (int c = 0; c < 4; ++c) { a1[c] = h1[c * 64 + lane]; }

        float hh0 = 0.f, hh1 = 0.f;
#pragma unroll
        for (int c = 0; c < 4; ++c) {
            hh0 += a0[c].x * a0[c].x + a0[c].y * a0[c].y +
                   a0[c].z * a0[c].z + a0[c].w * a0[c].w;
            hh1 += a1[c].x * a1[c].x + a1[c].y * a1[c].y +
                   a1[c].z * a1[c].z + a1[c].w * a1[c].w;
        }

        float d0[EPB], d1[EPB];
#pragma unroll
        for (int e = 0; e < EPB; ++e) {
            float s0 = 0.f, s1 = 0.f;
#pragma unroll
            for (int c = 0; c < 4; ++c) {
                float4 kv = kl[e * 256 + c * 64 + lane];
                s0 += a0[c].x * kv.x + a0[c].y * kv.y +
                      a0[c].z * kv.z + a0[c].w * kv.w;
                s1 += a1[c].x * kv.x + a1[c].y * kv.y +
                      a1[c].z * kv.z + a1[c].w * kv.w;
            }
            d0[e] = s0; d1[e] = s1;
        }

        // DPP reductions (VALU pipe) -> totals in lane 63
        hh0 = wave_sum63(hh0);
        hh1 = wave_sum63(hh1);
#pragma unroll
        for (int e = 0; e < EPB; ++e) { d0[e] = wave_sum63(d0[e]); }
#pragma unroll
        for (int e = 0; e < EPB; ++e) { d1[e] = wave_sum63(d1[e]); }

        if (lane == 63) {
            epilogue(b, t0, hh0, d0, out_gid, out_w);
            if (has1) epilogue(b, t1, hh1, d1, out_gid, out_w);
        }
    }
}

extern "C" void kernel_launch(void* const* d_in, const int* in_sizes, int n_in,
                              void* d_out, int out_size, void* d_ws, size_t ws_size,
                              hipStream_t stream) {
    const float* h     = (const float*)d_in[0];
    const int*   op_id = (const int*)  d_in[1];
    const float* ek    = (const float*)d_in[2];

    int ntok  = in_sizes[1];           // B*T tokens
    int nrows = NB * EPB;              // 512 key rows

    // ws layout: rk (512 f) | cnt (64 i) | list (NB*ntok i)
    float* rk   = (float*)d_ws;
    int*   cnt  = (int*)(rk + 512);
    int*   list = cnt + 64;

    float* out_gid = (float*)d_out;
    float* out_w   = out_gid + (size_t)ntok * KTOP;

    int blocks1 = (nrows * 64 + 255) / 256;
    key_rnorm_kernel<<<blocks1, 256, 0, stream>>>(ek, rk, cnt, nrows);

    compact_kernel<<<(ntok + 255) / 256, 256, 0, stream>>>(op_id, cnt, list, ntok);

    router_kernel<<<NB * PARTS, 256, 0, stream>>>(h, ek, rk, cnt, list,
                                                  out_gid, out_w, ntok);
}

// Round 6
// 145.788 us; speedup vs baseline: 1.2523x; 1.0044x over previous
//
#include <hip/hip_runtime.h>
#include <cmath>

#define EMBED   1024
#define EPB     8
#define NB      64
#define KTOP    2
#define PARTS   8           // blocks per bucket in kernel C (512 blocks total)

// ---------------------------------------------------------------------------
// DPP wave64 sum -> total lands in lane 63 (VALU pipe, DS stays free).
// ---------------------------------------------------------------------------
template <int CTRL>
static __device__ __forceinline__ float dpp_mov(float v) {
    return __int_as_float(
        __builtin_amdgcn_update_dpp(0, __float_as_int(v), CTRL, 0xf, 0xf, true));
}
static __device__ __forceinline__ float wave_sum63(float x) {
    x += dpp_mov<0x111>(x);   // row_shr:1
    x += dpp_mov<0x112>(x);   // row_shr:2
    x += dpp_mov<0x114>(x);   // row_shr:4
    x += dpp_mov<0x118>(x);   // row_shr:8
    x += dpp_mov<0x142>(x);   // row_bcast15
    x += dpp_mov<0x143>(x);   // row_bcast31 -> lane63 = wave total
    return x;
}

// ---------------------------------------------------------------------------
// Kernel A: write pre-normalized keys kn = k / max(||k||,eps) to ws.
// One wave per row (512 rows). Also zeroes the 64 bucket counters.
// ---------------------------------------------------------------------------
__global__ void key_norm_kernel(const float* __restrict__ ek,
                                float* __restrict__ kn,
                                int* __restrict__ cnt, int nrows) {
    if (blockIdx.x == 0 && threadIdx.x < NB) cnt[threadIdx.x] = 0;
    int wave = (int)((blockIdx.x * blockDim.x + threadIdx.x) >> 6);
    int lane = threadIdx.x & 63;
    if (wave >= nrows) return;
    const float4* row = (const float4*)(ek + (size_t)wave * EMBED);
    float4 v[4];
    float s = 0.f;
#pragma unroll
    for (int c = 0; c < 4; ++c) {
        v[c] = row[c * 64 + lane];
        s += v[c].x * v[c].x + v[c].y * v[c].y + v[c].z * v[c].z + v[c].w * v[c].w;
    }
#pragma unroll
    for (int off = 32; off; off >>= 1) s += __shfl_xor(s, off, 64);
    float r = 1.0f / fmaxf(sqrtf(s), 1e-12f);
    float4* out = (float4*)(kn + (size_t)wave * EMBED);
#pragma unroll
    for (int c = 0; c < 4; ++c) {
        float4 o = v[c];
        o.x *= r; o.y *= r; o.z *= r; o.w *= r;
        out[c * 64 + lane] = o;
    }
}

// ---------------------------------------------------------------------------
// Kernel B: bucket compaction.
// ---------------------------------------------------------------------------
__global__ void compact_kernel(const int* __restrict__ op_id,
                               int* __restrict__ cnt,
                               int* __restrict__ list, int ntok) {
    int t = blockIdx.x * blockDim.x + threadIdx.x;
    if (t >= ntok) return;
    int b = op_id[t];
    b = min(max(b, 0), NB - 1);
    int slot = atomicAdd(&cnt[b], 1);
    list[(size_t)b * ntok + slot] = t;
}

// ---------------------------------------------------------------------------
// Epilogue (exec-masked on lane 63). No max-subtract: |score| <= 1 since both
// vectors are unit norm and TAU=1, so exp() is in [0.37, 2.72] -- safe, and
// softmax is shift-invariant. __expf is 2 insts vs libm expf's ~10.
// ---------------------------------------------------------------------------
static __device__ __forceinline__ void epilogue(
        int b, int t, float hh, const float* dot,
        float* __restrict__ out_gid, float* __restrict__ out_w) {
    float rh = 1.0f / fmaxf(sqrtf(hh), 1e-12f);
    float ex[EPB];
    float Z = 0.f;
#pragma unroll
    for (int e = 0; e < EPB; ++e) { ex[e] = __expf(dot[e] * rh); Z += ex[e]; }
    int i1 = 0;
#pragma unroll
    for (int e = 1; e < EPB; ++e) if (ex[e] > ex[i1]) i1 = e;
    int i2 = (i1 == 0) ? 1 : 0;
#pragma unroll
    for (int e = 0; e < EPB; ++e)
        if (e != i1 && ex[e] > ex[i2]) i2 = e;
    float p1 = ex[i1] / Z;
    float p2 = ex[i2] / Z;
    float wsum = p1 + p2 + 1e-9f;
    *(float2*)(out_gid + (size_t)t * KTOP) =
        make_float2((float)(b * EPB + i1), (float)(b * EPB + i2));
    *(float2*)(out_w   + (size_t)t * KTOP) =
        make_float2(p1 / wsum, p2 / wsum);
}

// ---------------------------------------------------------------------------
// Kernel C: bucket-pinned router. 4 tokens per wave-iteration.
// R6 vs R5 -- attack load->use serialization:
//   * ALL 16 h float4 loads issued into a register array before ANY use
//     (one vmcnt batch instead of interleaved load-wait-use).
//   * key ds_reads batched 8-at-a-time per K-chunk, then 144 FMAs
//     (amortizes the ~120cyc DS latency 8x; R5 paid it per read).
//   * 4 tokens share each key read; keys pre-normalized (no rk pass).
//   * PARTS=8: 512 blocks * 4 waves = 2048 waves (8/CU), 2 iters each.
// ---------------------------------------------------------------------------
__global__ __launch_bounds__(256, 2) void router_kernel(
        const float* __restrict__ h,
        const float* __restrict__ kn,
        const int*   __restrict__ cnt,
        const int*   __restrict__ list,
        float* __restrict__ out_gid,
        float* __restrict__ out_w,
        int ntok) {
    __shared__ float4 kl[EPB * 256];            // 32 KB normalized keys

    const int b    = blockIdx.x >> 3;           // bucket
    const int part = blockIdx.x & (PARTS - 1);
    const int tid  = threadIdx.x;
    const int wv   = tid >> 6;
    const int lane = tid & 63;

    // stage bucket's normalized keys: 2048 float4 / 256 thr = 8 each
    const float4* k4 = (const float4*)kn + (size_t)b * (EPB * 256);
#pragma unroll
    for (int r = 0; r < 8; ++r) {
        int idx = r * 256 + tid;
        kl[idx] = k4[idx];
    }
    __syncthreads();

    const int  n  = cnt[b];
    const int  q  = part * 4 + wv;              // wave id in bucket [0,32)
    const int* ml = list + (size_t)b * ntok;

    for (int base = 4 * q; base < n; base += 4 * 32) {
        // --- token ids (tail slots duplicate t[0]; duplicate writes are
        //     identical values, harmless) ---
        int t[4];
        t[0] = ml[base];
#pragma unroll
        for (int j = 1; j < 4; ++j)
            t[j] = (base + j < n) ? ml[base + j] : t[0];

        // --- batch ALL h loads first: 16 float4, one vmcnt batch ---
        float4 a[4][4];
#pragma unroll
        for (int j = 0; j < 4; ++j) {
            const float4* hr = (const float4*)h + (size_t)t[j] * 256;
#pragma unroll
            for (int c = 0; c < 4; ++c)
                a[j][c] = hr[c * 64 + lane];
        }

        float hh[4] = {0.f, 0.f, 0.f, 0.f};
        float d[4][EPB];
#pragma unroll
        for (int j = 0; j < 4; ++j)
#pragma unroll
            for (int e = 0; e < EPB; ++e) d[j][e] = 0.f;

        // --- K-chunks: batch 8 key ds_reads, then 144 FMAs ---
#pragma unroll
        for (int c = 0; c < 4; ++c) {
            float4 kv[EPB];
#pragma unroll
            for (int e = 0; e < EPB; ++e)
                kv[e] = kl[e * 256 + c * 64 + lane];
#pragma unroll
            for (int j = 0; j < 4; ++j) {
                float4 av = a[j][c];
                hh[j] += av.x * av.x + av.y * av.y + av.z * av.z + av.w * av.w;
#pragma unroll
                for (int e = 0; e < EPB; ++e)
                    d[j][e] += av.x * kv[e].x + av.y * kv[e].y +
                               av.z * kv[e].z + av.w * kv[e].w;
            }
        }

        // --- 36 DPP reductions (totals land in lane 63) ---
#pragma unroll
        for (int j = 0; j < 4; ++j) {
            hh[j] = wave_sum63(hh[j]);
#pragma unroll
            for (int e = 0; e < EPB; ++e) d[j][e] = wave_sum63(d[j][e]);
        }

        if (lane == 63) {
#pragma unroll
            for (int j = 0; j < 4; ++j)
                if (base + j < n || j == 0)
                    epilogue(b, t[j], hh[j], d[j], out_gid, out_w);
        }
    }
}

extern "C" void kernel_launch(void* const* d_in, const int* in_sizes, int n_in,
                              void* d_out, int out_size, void* d_ws, size_t ws_size,
                              hipStream_t stream) {
    const float* h     = (const float*)d_in[0];
    const int*   op_id = (const int*)  d_in[1];
    const float* ek    = (const float*)d_in[2];

    int ntok  = in_sizes[1];           // B*T tokens
    int nrows = NB * EPB;              // 512 key rows

    // ws layout: kn (512*1024 f = 2 MB) | cnt (64 i) | list (NB*ntok i)
    float* kn   = (float*)d_ws;
    int*   cnt  = (int*)(kn + (size_t)nrows * EMBED);
    int*   list = cnt + 64;

    float* out_gid = (float*)d_out;
    float* out_w   = out_gid + (size_t)ntok * KTOP;

    int blocks1 = (nrows * 64 + 255) / 256;
    key_norm_kernel<<<blocks1, 256, 0, stream>>>(ek, kn, cnt, nrows);

    compact_kernel<<<(ntok + 255) / 256, 256, 0, stream>>>(op_id, cnt, list, ntok);

    router_kernel<<<NB * PARTS, 256, 0, stream>>>(h, kn, cnt, list,
                                                  out_gid, out_w, ntok);
}